// Round 2
// baseline (1292.380 us; speedup 1.0000x reference)
//
#include <hip/hip_runtime.h>

#define HH 256
#define WW 384
#define HWSZ (HH*WW)
#define NL 3
#define ANGN 7
#define A2N 49
#define NBATCH 2
#define RANKN 4
#define CN 3
#define RCN (RANKN*CN)

// padded input: each channel image is HH rows x WP cols, col 0 <-> x = -4,
// cols [-4,-1] replicate x=0, cols [384,387] replicate x=383.
#define WP 392
#define CHS (HH*WP)                 // floats per padded channel image
#define NCH (NBATCH*NL*RCN)         // 72 channel images
#define QPR (WP/4)                  // 98 float4 quads per padded row

#define WPX 8                       // pixels per thread (main kernel)
#define GX (WW/WPX)                 // 48 pixel-groups per row
#define PBN ((HH*GX)/256)           // 48 pixel-blocks per (n,k,c)

// ---------------- fallback: round-0 kernel (used if workspace too small) --------
__global__ __launch_bounds__(256) void multilayer_kernel(
    const float* __restrict__ low_rank,
    const float* __restrict__ planes,
    float* __restrict__ out)
{
    int b = blockIdx.x;
    int pb = b % (HWSZ / 256);
    int na = b / (HWSZ / 256);
    int a  = na % A2N;
    int n  = na / A2N;

    int tid = pb * 256 + (int)threadIdx.x;
    int y = tid / WW;
    int x = tid % WW;
    float xf = (float)x, yf = (float)y;

    int lidx = a % ANGN - 3;
    int kidx = a / ANGN - 3;
    float sxa = -(float)lidx * (1.0f / WW) * 0.5f * (float)(WW - 1);
    float sya = -(float)kidx * (1.0f / HH) * 0.5f * (float)(HH - 1);

    float acc[RCN];
#pragma unroll
    for (int i = 0; i < RCN; i++) acc[i] = 1.0f;

#pragma unroll
    for (int l = 0; l < NL; l++) {
        float p = planes[n * NL + l];
        float X = fminf(fmaxf(xf + p * sxa, 0.0f), (float)(WW - 1));
        float Y = fminf(fmaxf(yf + p * sya, 0.0f), (float)(HH - 1));
        float x0f = floorf(X), y0f = floorf(Y);
        int x0 = (int)x0f, y0 = (int)y0f;
        int x1 = min(x0 + 1, WW - 1);
        int y1 = min(y0 + 1, HH - 1);
        float wx = X - x0f, wy = Y - y0f;
        float w00 = (1.0f - wx) * (1.0f - wy);
        float w01 = wx * (1.0f - wy);
        float w10 = (1.0f - wx) * wy;
        float w11 = wx * wy;

        const float* img = low_rank + (size_t)((n * NL + l) * RCN) * HWSZ;
        const float* r0 = img + y0 * WW;
        const float* r1 = img + y1 * WW;

#pragma unroll
        for (int rc = 0; rc < RCN; rc++) {
            float v00 = r0[rc * HWSZ + x0];
            float v01 = r0[rc * HWSZ + x1];
            float v10 = r1[rc * HWSZ + x0];
            float v11 = r1[rc * HWSZ + x1];
            float s = v00 * w00 + v01 * w01 + v10 * w10 + v11 * w11;
            acc[rc] *= s;
        }
    }

    int obase = ((n * A2N + a) * CN) * HWSZ + y * WW + x;
#pragma unroll
    for (int c = 0; c < CN; c++) {
        float s = acc[0 * CN + c] + acc[1 * CN + c] + acc[2 * CN + c] + acc[3 * CN + c];
        out[obase + c * HWSZ] = 0.25f * s;
    }
}

// ---------------- pre-pass: replicate-pad, 2 quads (32B) per thread -------------
__global__ __launch_bounds__(256) void pad_kernel(const float* __restrict__ src,
                                                  float* __restrict__ dst)
{
    int idx = blockIdx.x * 256 + (int)threadIdx.x;   // pair id, < NCH*HH*49
    int row = idx / 49;                               // ch*HH + y
    int qp  = idx - row * 49;                         // quad pair 0..48
    const float* s = src + (size_t)row * WW;
    float4* d = (float4*)dst + (size_t)row * QPR + qp * 2;
    float4 v0, v1;
    if (qp == 0) {
        float t = s[0];
        v0 = make_float4(t, t, t, t);                 // cols -4..-1
        v1 = *(const float4*)(s);                     // cols 0..3
    } else if (qp == 48) {
        v0 = *(const float4*)(s + 380);               // cols 380..383
        float t = s[WW - 1];
        v1 = make_float4(t, t, t, t);                 // cols 384..387
    } else {
        v0 = *(const float4*)(s + (2 * qp - 1) * 4);
        v1 = *(const float4*)(s + (2 * qp) * 4);
    }
    d[0] = v0;
    d[1] = v1;
}

// lerp helpers over a staged 16-float window (indices 2..13 valid)
#define LERP1(HL, I, WX) ((HL)[I] + (WX) * ((HL)[(I)+1] - (HL)[I]))
#define PROD_SET(P, HL, K, WX) do {                   \
    P[0] = LERP1(HL, (K)+0, WX); P[1] = LERP1(HL, (K)+1, WX); \
    P[2] = LERP1(HL, (K)+2, WX); P[3] = LERP1(HL, (K)+3, WX); \
    P[4] = LERP1(HL, (K)+4, WX); P[5] = LERP1(HL, (K)+5, WX); \
    P[6] = LERP1(HL, (K)+6, WX); P[7] = LERP1(HL, (K)+7, WX); \
} while (0)
#define PROD_MUL(P, HL, K, WX) do {                   \
    P[0] *= LERP1(HL, (K)+0, WX); P[1] *= LERP1(HL, (K)+1, WX); \
    P[2] *= LERP1(HL, (K)+2, WX); P[3] *= LERP1(HL, (K)+3, WX); \
    P[4] *= LERP1(HL, (K)+4, WX); P[5] *= LERP1(HL, (K)+5, WX); \
    P[6] *= LERP1(HL, (K)+6, WX); P[7] *= LERP1(HL, (K)+7, WX); \
} while (0)
#define ACC_FMA(A, P, HL, K, WX) do {                 \
    A[0] = fmaf(P[0], LERP1(HL, (K)+0, WX), A[0]); \
    A[1] = fmaf(P[1], LERP1(HL, (K)+1, WX), A[1]); \
    A[2] = fmaf(P[2], LERP1(HL, (K)+2, WX), A[2]); \
    A[3] = fmaf(P[3], LERP1(HL, (K)+3, WX), A[3]); \
    A[4] = fmaf(P[4], LERP1(HL, (K)+4, WX), A[4]); \
    A[5] = fmaf(P[5], LERP1(HL, (K)+5, WX), A[5]); \
    A[6] = fmaf(P[6], LERP1(HL, (K)+6, WX), A[6]); \
    A[7] = fmaf(P[7], LERP1(HL, (K)+7, WX), A[7]); \
} while (0)

// stage one channel row-pair and vertical-lerp into HL[2..13]
#define STAGE(HL, L) do {                                                  \
    const float* cb = basen + (size_t)((L) * RCN + r * CN + c) * CHS;      \
    const float4* q0 = (const float4*)(cb + voff0[L]);                     \
    const float4* q1 = (const float4*)(cb + voff1[L]);                     \
    float4 a0 = q0[0], a1 = q0[1], a2 = q0[2], a3 = q0[3];                 \
    float4 b0 = q1[0], b1 = q1[1], b2 = q1[2], b3 = q1[3];                 \
    float w = wy[L];                                                       \
    HL[2]  = a0.z + w * (b0.z - a0.z);  HL[3]  = a0.w + w * (b0.w - a0.w); \
    HL[4]  = a1.x + w * (b1.x - a1.x);  HL[5]  = a1.y + w * (b1.y - a1.y); \
    HL[6]  = a1.z + w * (b1.z - a1.z);  HL[7]  = a1.w + w * (b1.w - a1.w); \
    HL[8]  = a2.x + w * (b2.x - a2.x);  HL[9]  = a2.y + w * (b2.y - a2.y); \
    HL[10] = a2.z + w * (b2.z - a2.z);  HL[11] = a2.w + w * (b2.w - a2.w); \
    HL[12] = a3.x + w * (b3.x - a3.x);  HL[13] = a3.y + w * (b3.y - a3.y); \
} while (0)

#define SWITCH_SET(P, HL, LI, J) do {                                      \
    float wx = wxl[LI][J];                                                 \
    switch (i0l[LI][J]) {                                                  \
        case 2:  PROD_SET(P, HL, 2, wx); break;                            \
        case 3:  PROD_SET(P, HL, 3, wx); break;                            \
        case 4:  PROD_SET(P, HL, 4, wx); break;                            \
        default: PROD_SET(P, HL, 5, wx); break;                            \
    }                                                                      \
} while (0)
#define SWITCH_MUL(P, HL, LI, J) do {                                      \
    float wx = wxl[LI][J];                                                 \
    switch (i0l[LI][J]) {                                                  \
        case 2:  PROD_MUL(P, HL, 2, wx); break;                            \
        case 3:  PROD_MUL(P, HL, 3, wx); break;                            \
        case 4:  PROD_MUL(P, HL, 4, wx); break;                            \
        default: PROD_MUL(P, HL, 5, wx); break;                            \
    }                                                                      \
} while (0)
#define SWITCH_ACC(A, P, HL, LI, J) do {                                   \
    float wx = wxl[LI][J];                                                 \
    switch (i0l[LI][J]) {                                                  \
        case 2:  ACC_FMA(A, P, HL, 2, wx); break;                          \
        case 3:  ACC_FMA(A, P, HL, 3, wx); break;                          \
        case 4:  ACC_FMA(A, P, HL, 4, wx); break;                          \
        default: ACC_FMA(A, P, HL, 5, wx); break;                          \
    }                                                                      \
} while (0)

// ---------------- main: 8 pixels x 7 views, one (n,k,c) per block group ---------
// grid = 2016 blocks = 2n * 3c * 7k * 48pb; 8*252 XCD-bijective swizzle.
__global__ __launch_bounds__(256, 3) void ml8_kernel(const float* __restrict__ padbuf,
                                                     const float* __restrict__ planes,
                                                     float* __restrict__ out)
{
    int bid = (int)blockIdx.x;
    int g   = (bid & 7) * 252 + (bid >> 3);      // bijective: 2016 = 8*252
    int pb  = g % PBN;
    int t   = g / PBN;
    int k   = t % ANGN;
    int nc  = t / ANGN;
    int c   = nc % CN;
    int n   = nc / CN;

    int g8 = pb * 256 + (int)threadIdx.x;        // [0, 12288)
    int xg = g8 % GX;
    int y  = g8 / GX;
    int xb = xg * WPX;                           // first of 8 pixels

    const float syk = -(float)(k - 3) * (0.5f * (float)(HH - 1) / (float)HH);

    float wy[NL];
    int   voff0[NL], voff1[NL];
    float wxl[NL][ANGN];
    int   i0l[NL][ANGN];

#pragma unroll
    for (int l = 0; l < NL; l++) {
        float p  = planes[n * NL + l];
        float Y  = fminf(fmaxf((float)y + p * syk, 0.0f), (float)(HH - 1));
        float yf = floorf(Y);
        int y0   = (int)yf;
        if (y0 > HH - 2) y0 = HH - 2;
        wy[l]    = Y - (float)y0;
        voff0[l] = y0 * WP + xb;                 // window col (xb-4) -> pad idx xb
        voff1[l] = voff0[l] + WP;
#pragma unroll
        for (int j = 0; j < ANGN; j++) {
            float sxj = -(float)(j - 3) * (0.5f * (float)(WW - 1) / (float)WW);
            float dx  = p * sxj;                 // |dx| < 1.5  ->  i0 in {2..5}
            float oxf = floorf(dx);
            float wx  = dx - oxf;
            wxl[l][j] = __uint_as_float(__builtin_amdgcn_readfirstlane(__float_as_uint(wx)));
            i0l[l][j] = __builtin_amdgcn_readfirstlane((int)oxf + 4);
        }
    }

    const float* basen = padbuf + (size_t)(n * NL * RCN) * CHS;

    float acc[ANGN][WPX];
#pragma unroll
    for (int j = 0; j < ANGN; j++)
#pragma unroll
        for (int px = 0; px < WPX; px++) acc[j][px] = 0.0f;

#pragma unroll 1
    for (int r = 0; r < RANKN; r++) {
        float h0[16], h1[16], h2[16];            // indices 2..13 valid
        STAGE(h0, 0);
        STAGE(h1, 1);
        STAGE(h2, 2);

#pragma unroll
        for (int j = 0; j < ANGN; j++) {
            float prod[WPX];
            SWITCH_SET(prod, h0, 0, j);
            SWITCH_MUL(prod, h1, 1, j);
            SWITCH_ACC(acc[j], prod, h2, 2, j);
        }
    }

    size_t obase = ((size_t)((n * A2N + k * ANGN) * CN + c)) * HWSZ
                 + (size_t)y * WW + xb;
#pragma unroll
    for (int j = 0; j < ANGN; j++) {
        float* op = out + obase + (size_t)(j * CN) * HWSZ;
        float4 v0 = make_float4(acc[j][0] * 0.25f, acc[j][1] * 0.25f,
                                acc[j][2] * 0.25f, acc[j][3] * 0.25f);
        float4 v1 = make_float4(acc[j][4] * 0.25f, acc[j][5] * 0.25f,
                                acc[j][6] * 0.25f, acc[j][7] * 0.25f);
        *(float4*)(op)     = v0;
        *(float4*)(op + 4) = v1;
    }
}

extern "C" void kernel_launch(void* const* d_in, const int* in_sizes, int n_in,
                              void* d_out, int out_size, void* d_ws, size_t ws_size,
                              hipStream_t stream) {
    const float* low_rank = (const float*)d_in[0];
    const float* planes   = (const float*)d_in[1];
    float* out = (float*)d_out;

    size_t need = (size_t)NCH * CHS * sizeof(float);   // 28,901,376 B
    if (d_ws != nullptr && ws_size >= need) {
        float* padbuf = (float*)d_ws;
        int pad_blocks = (NCH * HH * 49) / 256;        // 3528, exact
        pad_kernel<<<pad_blocks, 256, 0, stream>>>(low_rank, padbuf);
        int ml_blocks = NBATCH * CN * ANGN * PBN;      // 2016
        ml8_kernel<<<ml_blocks, 256, 0, stream>>>(padbuf, planes, out);
    } else {
        int blocks = NBATCH * A2N * (HWSZ / 256);
        multilayer_kernel<<<blocks, 256, 0, stream>>>(low_rank, planes, out);
    }
}

// Round 4
// 210.426 us; speedup vs baseline: 6.1417x; 6.1417x over previous
//
#include <hip/hip_runtime.h>

#define HH 256
#define WW 384
#define HWSZ (HH*WW)
#define NL 3
#define ANGN 7
#define A2N 49
#define NBATCH 2
#define RANKN 4
#define CN 3
#define RCN (RANKN*CN)

// padded input: each channel image is HH rows x WP cols, col 0 <-> x = -4,
// cols [-4,-1] replicate x=0, cols [384,387] replicate x=383.
#define WP 392
#define CHS (HH*WP)                 // floats per padded channel image
#define NCH (NBATCH*NL*RCN)         // 72 channel images
#define QPR (WP/4)                  // 98 float4 quads per padded row

#define WPX 8                       // pixels per thread (main kernel)
#define GX (WW/WPX)                 // 48 pixel-groups per row
#define PBN ((HH*GX)/256)           // 48 pixel-blocks per (n,k,c)

// ---------------- fallback: round-0 kernel (used if workspace too small) --------
__global__ __launch_bounds__(256) void multilayer_kernel(
    const float* __restrict__ low_rank,
    const float* __restrict__ planes,
    float* __restrict__ out)
{
    int b = blockIdx.x;
    int pb = b % (HWSZ / 256);
    int na = b / (HWSZ / 256);
    int a  = na % A2N;
    int n  = na / A2N;

    int tid = pb * 256 + (int)threadIdx.x;
    int y = tid / WW;
    int x = tid % WW;
    float xf = (float)x, yf = (float)y;

    int lidx = a % ANGN - 3;
    int kidx = a / ANGN - 3;
    float sxa = -(float)lidx * (1.0f / WW) * 0.5f * (float)(WW - 1);
    float sya = -(float)kidx * (1.0f / HH) * 0.5f * (float)(HH - 1);

    float acc[RCN];
#pragma unroll
    for (int i = 0; i < RCN; i++) acc[i] = 1.0f;

#pragma unroll
    for (int l = 0; l < NL; l++) {
        float p = planes[n * NL + l];
        float X = fminf(fmaxf(xf + p * sxa, 0.0f), (float)(WW - 1));
        float Y = fminf(fmaxf(yf + p * sya, 0.0f), (float)(HH - 1));
        float x0f = floorf(X), y0f = floorf(Y);
        int x0 = (int)x0f, y0 = (int)y0f;
        int x1 = min(x0 + 1, WW - 1);
        int y1 = min(y0 + 1, HH - 1);
        float wx = X - x0f, wy = Y - y0f;
        float w00 = (1.0f - wx) * (1.0f - wy);
        float w01 = wx * (1.0f - wy);
        float w10 = (1.0f - wx) * wy;
        float w11 = wx * wy;

        const float* img = low_rank + (size_t)((n * NL + l) * RCN) * HWSZ;
        const float* r0 = img + y0 * WW;
        const float* r1 = img + y1 * WW;

#pragma unroll
        for (int rc = 0; rc < RCN; rc++) {
            float v00 = r0[rc * HWSZ + x0];
            float v01 = r0[rc * HWSZ + x1];
            float v10 = r1[rc * HWSZ + x0];
            float v11 = r1[rc * HWSZ + x1];
            float s = v00 * w00 + v01 * w01 + v10 * w10 + v11 * w11;
            acc[rc] *= s;
        }
    }

    int obase = ((n * A2N + a) * CN) * HWSZ + y * WW + x;
#pragma unroll
    for (int c = 0; c < CN; c++) {
        float s = acc[0 * CN + c] + acc[1 * CN + c] + acc[2 * CN + c] + acc[3 * CN + c];
        out[obase + c * HWSZ] = 0.25f * s;
    }
}

// ---------------- pre-pass: replicate-pad, 2 quads (32B) per thread -------------
__global__ __launch_bounds__(256) void pad_kernel(const float* __restrict__ src,
                                                  float* __restrict__ dst)
{
    int idx = blockIdx.x * 256 + (int)threadIdx.x;   // pair id, < NCH*HH*49
    int row = idx / 49;                               // ch*HH + y
    int qp  = idx - row * 49;                         // quad pair 0..48
    const float* s = src + (size_t)row * WW;
    float4* d = (float4*)dst + (size_t)row * QPR + qp * 2;
    float4 v0, v1;
    if (qp == 0) {
        float t = s[0];
        v0 = make_float4(t, t, t, t);                 // cols -4..-1
        v1 = *(const float4*)(s);                     // cols 0..3
    } else if (qp == 48) {
        v0 = *(const float4*)(s + 380);               // cols 380..383
        float t = s[WW - 1];
        v1 = make_float4(t, t, t, t);                 // cols 384..387
    } else {
        v0 = *(const float4*)(s + (2 * qp - 1) * 4);
        v1 = *(const float4*)(s + (2 * qp) * 4);
    }
    d[0] = v0;
    d[1] = v1;
}

// lerp helpers over a staged 16-float window (indices 2..13 valid)
#define LERP1(HL, I, WX) ((HL)[I] + (WX) * ((HL)[(I)+1] - (HL)[I]))
#define PROD_SET(P, HL, K, WX) do {                   \
    P[0] = LERP1(HL, (K)+0, WX); P[1] = LERP1(HL, (K)+1, WX); \
    P[2] = LERP1(HL, (K)+2, WX); P[3] = LERP1(HL, (K)+3, WX); \
    P[4] = LERP1(HL, (K)+4, WX); P[5] = LERP1(HL, (K)+5, WX); \
    P[6] = LERP1(HL, (K)+6, WX); P[7] = LERP1(HL, (K)+7, WX); \
} while (0)
#define PROD_MUL(P, HL, K, WX) do {                   \
    P[0] *= LERP1(HL, (K)+0, WX); P[1] *= LERP1(HL, (K)+1, WX); \
    P[2] *= LERP1(HL, (K)+2, WX); P[3] *= LERP1(HL, (K)+3, WX); \
    P[4] *= LERP1(HL, (K)+4, WX); P[5] *= LERP1(HL, (K)+5, WX); \
    P[6] *= LERP1(HL, (K)+6, WX); P[7] *= LERP1(HL, (K)+7, WX); \
} while (0)
#define ACC_FMA(A, P, HL, K, WX) do {                 \
    A[0] = fmaf(P[0], LERP1(HL, (K)+0, WX), A[0]); \
    A[1] = fmaf(P[1], LERP1(HL, (K)+1, WX), A[1]); \
    A[2] = fmaf(P[2], LERP1(HL, (K)+2, WX), A[2]); \
    A[3] = fmaf(P[3], LERP1(HL, (K)+3, WX), A[3]); \
    A[4] = fmaf(P[4], LERP1(HL, (K)+4, WX), A[4]); \
    A[5] = fmaf(P[5], LERP1(HL, (K)+5, WX), A[5]); \
    A[6] = fmaf(P[6], LERP1(HL, (K)+6, WX), A[6]); \
    A[7] = fmaf(P[7], LERP1(HL, (K)+7, WX), A[7]); \
} while (0)

// stage one channel row-pair and vertical-lerp into HL[2..13]
#define STAGE(HL, L) do {                                                  \
    const float* cb = basen + (size_t)((L) * RCN + r * CN + c) * CHS;      \
    const float4* q0 = (const float4*)(cb + voff0[L]);                     \
    const float4* q1 = (const float4*)(cb + voff1[L]);                     \
    float4 a0 = q0[0], a1 = q0[1], a2 = q0[2], a3 = q0[3];                 \
    float4 b0 = q1[0], b1 = q1[1], b2 = q1[2], b3 = q1[3];                 \
    float w = wy[L];                                                       \
    HL[2]  = a0.z + w * (b0.z - a0.z);  HL[3]  = a0.w + w * (b0.w - a0.w); \
    HL[4]  = a1.x + w * (b1.x - a1.x);  HL[5]  = a1.y + w * (b1.y - a1.y); \
    HL[6]  = a1.z + w * (b1.z - a1.z);  HL[7]  = a1.w + w * (b1.w - a1.w); \
    HL[8]  = a2.x + w * (b2.x - a2.x);  HL[9]  = a2.y + w * (b2.y - a2.y); \
    HL[10] = a2.z + w * (b2.z - a2.z);  HL[11] = a2.w + w * (b2.w - a2.w); \
    HL[12] = a3.x + w * (b3.x - a3.x);  HL[13] = a3.y + w * (b3.y - a3.y); \
} while (0)

// NOTE: LI and J must be integer LITERALS at every use site — this keeps every
// array subscript compile-time-constant independent of unroll heuristics
// (round-2 post-mortem: compiler declined the j-loop unroll -> acc[j] went to
// scratch -> 2.5 GB of spill traffic, 1137 us).
#define SWITCH_SET(P, HL, LI, J) do {                                      \
    float wx = wxl[LI][J];                                                 \
    switch (i0l[LI][J]) {                                                  \
        case 2:  PROD_SET(P, HL, 2, wx); break;                            \
        case 3:  PROD_SET(P, HL, 3, wx); break;                            \
        case 4:  PROD_SET(P, HL, 4, wx); break;                            \
        default: PROD_SET(P, HL, 5, wx); break;                            \
    }                                                                      \
} while (0)
#define SWITCH_MUL(P, HL, LI, J) do {                                      \
    float wx = wxl[LI][J];                                                 \
    switch (i0l[LI][J]) {                                                  \
        case 2:  PROD_MUL(P, HL, 2, wx); break;                            \
        case 3:  PROD_MUL(P, HL, 3, wx); break;                            \
        case 4:  PROD_MUL(P, HL, 4, wx); break;                            \
        default: PROD_MUL(P, HL, 5, wx); break;                            \
    }                                                                      \
} while (0)
#define SWITCH_ACC(A, P, HL, LI, J) do {                                   \
    float wx = wxl[LI][J];                                                 \
    switch (i0l[LI][J]) {                                                  \
        case 2:  ACC_FMA(A, P, HL, 2, wx); break;                          \
        case 3:  ACC_FMA(A, P, HL, 3, wx); break;                          \
        case 4:  ACC_FMA(A, P, HL, 4, wx); break;                          \
        default: ACC_FMA(A, P, HL, 5, wx); break;                          \
    }                                                                      \
} while (0)

#define INIT_J(J) do {                                                     \
    acc[J][0] = 0.0f; acc[J][1] = 0.0f; acc[J][2] = 0.0f; acc[J][3] = 0.0f;\
    acc[J][4] = 0.0f; acc[J][5] = 0.0f; acc[J][6] = 0.0f; acc[J][7] = 0.0f;\
} while (0)

#define DO_J(J) do {                                                       \
    float prod[WPX];                                                       \
    SWITCH_SET(prod, h0, 0, J);                                            \
    SWITCH_MUL(prod, h1, 1, J);                                            \
    SWITCH_ACC(acc[J], prod, h2, 2, J);                                    \
} while (0)

#define STORE_J(J) do {                                                    \
    float* op = out + obase + (size_t)((J) * CN) * HWSZ;                   \
    *(float4*)(op)     = make_float4(acc[J][0] * 0.25f, acc[J][1] * 0.25f, \
                                     acc[J][2] * 0.25f, acc[J][3] * 0.25f);\
    *(float4*)(op + 4) = make_float4(acc[J][4] * 0.25f, acc[J][5] * 0.25f, \
                                     acc[J][6] * 0.25f, acc[J][7] * 0.25f);\
} while (0)

// ---------------- main: 8 pixels x 7 views, one (n,k,c) per block group ---------
// grid = 2016 blocks = 2n * 3c * 7k * 48pb; 8*252 XCD-bijective swizzle.
__global__ __launch_bounds__(256) void ml9_kernel(const float* __restrict__ padbuf,
                                                  const float* __restrict__ planes,
                                                  float* __restrict__ out)
{
    int bid = (int)blockIdx.x;
    int g   = (bid & 7) * 252 + (bid >> 3);      // bijective: 2016 = 8*252
    int pb  = g % PBN;
    int t   = g / PBN;
    int k   = t % ANGN;
    int nc  = t / ANGN;
    int c   = nc % CN;
    int n   = nc / CN;

    int g8 = pb * 256 + (int)threadIdx.x;        // [0, 12288)
    int xg = g8 % GX;
    int y  = g8 / GX;
    int xb = xg * WPX;                           // first of 8 pixels

    const float syk = -(float)(k - 3) * (0.5f * (float)(HH - 1) / (float)HH);

    float wy[NL];
    int   voff0[NL], voff1[NL];
    float wxl[NL][ANGN];
    int   i0l[NL][ANGN];

#pragma unroll
    for (int l = 0; l < NL; l++) {
        float p  = planes[n * NL + l];
        float Y  = fminf(fmaxf((float)y + p * syk, 0.0f), (float)(HH - 1));
        float yf = floorf(Y);
        int y0   = (int)yf;
        if (y0 > HH - 2) y0 = HH - 2;
        wy[l]    = Y - (float)y0;
        voff0[l] = y0 * WP + xb;                 // window col (xb-4) -> pad idx xb
        voff1[l] = voff0[l] + WP;
#pragma unroll
        for (int j = 0; j < ANGN; j++) {
            float sxj = -(float)(j - 3) * (0.5f * (float)(WW - 1) / (float)WW);
            float dx  = p * sxj;                 // |dx| < 1.5  ->  i0 in {2..5}
            float oxf = floorf(dx);
            float wx  = dx - oxf;
            wxl[l][j] = __uint_as_float(__builtin_amdgcn_readfirstlane(__float_as_uint(wx)));
            i0l[l][j] = __builtin_amdgcn_readfirstlane((int)oxf + 4);
        }
    }

    const float* basen = padbuf + (size_t)(n * NL * RCN) * CHS;

    float acc[ANGN][WPX];
    INIT_J(0); INIT_J(1); INIT_J(2); INIT_J(3); INIT_J(4); INIT_J(5); INIT_J(6);

#pragma unroll 1
    for (int r = 0; r < RANKN; r++) {
        float h0[16], h1[16], h2[16];            // indices 2..13 valid
        STAGE(h0, 0);
        STAGE(h1, 1);
        STAGE(h2, 2);

        DO_J(0); DO_J(1); DO_J(2); DO_J(3); DO_J(4); DO_J(5); DO_J(6);
    }

    size_t obase = ((size_t)((n * A2N + k * ANGN) * CN + c)) * HWSZ
                 + (size_t)y * WW + xb;
    STORE_J(0); STORE_J(1); STORE_J(2); STORE_J(3);
    STORE_J(4); STORE_J(5); STORE_J(6);
}

extern "C" void kernel_launch(void* const* d_in, const int* in_sizes, int n_in,
                              void* d_out, int out_size, void* d_ws, size_t ws_size,
                              hipStream_t stream) {
    const float* low_rank = (const float*)d_in[0];
    const float* planes   = (const float*)d_in[1];
    float* out = (float*)d_out;

    size_t need = (size_t)NCH * CHS * sizeof(float);   // 28,901,376 B
    if (d_ws != nullptr && ws_size >= need) {
        float* padbuf = (float*)d_ws;
        int pad_blocks = (NCH * HH * 49) / 256;        // 3528, exact
        pad_kernel<<<pad_blocks, 256, 0, stream>>>(low_rank, padbuf);
        int ml_blocks = NBATCH * CN * ANGN * PBN;      // 2016
        ml9_kernel<<<ml_blocks, 256, 0, stream>>>(padbuf, planes, out);
    } else {
        int blocks = NBATCH * A2N * (HWSZ / 256);
        multilayer_kernel<<<blocks, 256, 0, stream>>>(low_rank, planes, out);
    }
}